// Round 2
// baseline (797.679 us; speedup 1.0000x reference)
//
#include <hip/hip_runtime.h>

typedef __bf16 bf16;
typedef __bf16 bf16x8 __attribute__((ext_vector_type(8)));
typedef __bf16 bf16x4 __attribute__((ext_vector_type(4)));
typedef float  f32x4  __attribute__((ext_vector_type(4)));

#define B_   2
#define S_   4096
#define HID_ 2048
#define H_   16
#define D_   128
#define C_   256
#define NC_  16
#define M_   (B_*S_)   // 8192 rows
#define K_   2048      // inner dim of both big GEMMs

// ---------------------------------------------------------------------------
// f32 -> bf16 convert of x (16.7M elements), 8 per thread
// ---------------------------------------------------------------------------
__global__ void cvt_x_kernel(const float* __restrict__ x, bf16* __restrict__ xb) {
    int idx = (blockIdx.x * 256 + threadIdx.x) * 8;
    float4 f0 = *(const float4*)(x + idx);
    float4 f1 = *(const float4*)(x + idx + 4);
    bf16x8 o;
    o[0] = (bf16)f0.x; o[1] = (bf16)f0.y; o[2] = (bf16)f0.z; o[3] = (bf16)f0.w;
    o[4] = (bf16)f1.x; o[5] = (bf16)f1.y; o[6] = (bf16)f1.z; o[7] = (bf16)f1.w;
    *(bf16x8*)(xb + idx) = o;
}

// ---------------------------------------------------------------------------
// Transpose-convert weights to bf16 [N][K]:
// rows 0..6143 = w_qkv cols, 6144..8191 = w_gate cols, 8192..10239 = w_out cols
// ---------------------------------------------------------------------------
__global__ void cvt_w_kernel(const float* __restrict__ wqkv,
                             const float* __restrict__ wgate,
                             const float* __restrict__ wout,
                             bf16* __restrict__ wT) {
    __shared__ float tile[32][33];
    int k0 = blockIdx.x * 32, n0 = blockIdx.y * 32;
    const float* src; int ld, col0;
    if (n0 < 6144)      { src = wqkv;  ld = 6144; col0 = n0; }
    else if (n0 < 8192) { src = wgate; ld = 2048; col0 = n0 - 6144; }
    else                { src = wout;  ld = 2048; col0 = n0 - 8192; }
    int tx = threadIdx.x, ty = threadIdx.y;
#pragma unroll
    for (int i = 0; i < 4; i++) {
        int kk = ty + i * 8;
        tile[kk][tx] = src[(size_t)(k0 + kk) * ld + col0 + tx];
    }
    __syncthreads();
#pragma unroll
    for (int i = 0; i < 4; i++) {
        int nn = ty + i * 8;
        wT[(size_t)(n0 + nn) * K_ + k0 + tx] = (bf16)tile[tx][nn];
    }
}

// ---------------------------------------------------------------------------
// bf16 GEMM, C[M][N] = act( A[M][K] @ B[N][K]^T ).  128x128 tile, 4 waves
// (2x2 of 64x64), BK=32, single-buffered LDS, mfma 16x16x32 bf16.
// MODE 0: N=8192, split output into q/k/v (silu) and gate (sigmoid), bf16.
// MODE 1: N=2048, plain f32 output to d_out.
// ---------------------------------------------------------------------------
template <int MODE>
__global__ __launch_bounds__(256) void gemm_kernel(
        const bf16* __restrict__ A, const bf16* __restrict__ Bm,
        bf16* __restrict__ qo, bf16* __restrict__ ko,
        bf16* __restrict__ vo, bf16* __restrict__ go,
        float* __restrict__ out) {
    __shared__ __align__(16) bf16 As[128 * 40];
    __shared__ __align__(16) bf16 Bs[128 * 40];
    const int m0 = blockIdx.x * 128, n0 = blockIdx.y * 128;
    const int tid = threadIdx.x, lane = tid & 63, wid = tid >> 6;
    const int quad = lane >> 4, l15 = lane & 15;
    const int i0w = (wid >> 1) * 64, j0w = (wid & 1) * 64;
    f32x4 acc[4][4] = {};
    const int lrow = tid >> 1, lhalf = (tid & 1) * 16;
    const bf16* Ag = A  + (size_t)(m0 + lrow) * K_ + lhalf;
    const bf16* Bg = Bm + (size_t)(n0 + lrow) * K_ + lhalf;
    bf16* Asw = &As[lrow * 40 + lhalf];
    bf16* Bsw = &Bs[lrow * 40 + lhalf];

    for (int kb = 0; kb < K_; kb += 32) {
        bf16x8 a0 = *(const bf16x8*)(Ag + kb);
        bf16x8 a1 = *(const bf16x8*)(Ag + kb + 8);
        bf16x8 b0 = *(const bf16x8*)(Bg + kb);
        bf16x8 b1 = *(const bf16x8*)(Bg + kb + 8);
        *(bf16x8*)Asw = a0; *(bf16x8*)(Asw + 8) = a1;
        *(bf16x8*)Bsw = b0; *(bf16x8*)(Bsw + 8) = b1;
        __syncthreads();
        bf16x8 af[4], bfr[4];
#pragma unroll
        for (int t = 0; t < 4; t++)
            af[t] = *(const bf16x8*)&As[(i0w + t * 16 + l15) * 40 + quad * 8];
#pragma unroll
        for (int t = 0; t < 4; t++)
            bfr[t] = *(const bf16x8*)&Bs[(j0w + t * 16 + l15) * 40 + quad * 8];
#pragma unroll
        for (int ti = 0; ti < 4; ti++)
#pragma unroll
            for (int tj = 0; tj < 4; tj++)
                acc[ti][tj] = __builtin_amdgcn_mfma_f32_16x16x32_bf16(
                    af[ti], bfr[tj], acc[ti][tj], 0, 0, 0);
        __syncthreads();
    }

    if (MODE == 0) {
        bf16* outb = (n0 < 2048) ? qo : (n0 < 4096) ? ko : (n0 < 6144) ? vo : go;
        const bool silu = (n0 < 6144);
        const int cb = n0 & 2047;
#pragma unroll
        for (int ti = 0; ti < 4; ti++)
#pragma unroll
            for (int tj = 0; tj < 4; tj++)
#pragma unroll
                for (int r = 0; r < 4; r++) {
                    int row = m0 + i0w + ti * 16 + quad * 4 + r;
                    int col = cb + j0w + tj * 16 + l15;
                    float xv = acc[ti][tj][r];
                    float sg = 1.f / (1.f + __expf(-xv));
                    float av = silu ? xv * sg : sg;
                    outb[(size_t)row * 2048 + col] = (bf16)av;
                }
    } else {
#pragma unroll
        for (int ti = 0; ti < 4; ti++)
#pragma unroll
            for (int tj = 0; tj < 4; tj++)
#pragma unroll
                for (int r = 0; r < 4; r++) {
                    int row = m0 + i0w + ti * 16 + quad * 4 + r;
                    int col = n0 + j0w + tj * 16 + l15;
                    out[(size_t)row * 2048 + col] = acc[ti][tj][r];
                }
    }
}

// ---------------------------------------------------------------------------
// Transpose k and v per (b,h): [S][D] -> [D][S]   (bf16, LDS 64x64 tiles)
// grid (S/64, D/64, 2*32): z = arr*32 + bh
// ---------------------------------------------------------------------------
__global__ void transpose_kernel(const bf16* __restrict__ kin,
                                 const bf16* __restrict__ vin,
                                 bf16* __restrict__ kT, bf16* __restrict__ vT) {
    __shared__ bf16 tile[64][65];
    int x0 = blockIdx.x * 64, d0 = blockIdx.y * 64;
    int z = blockIdx.z, arr = z >> 5, bh = z & 31, b = bh >> 4, h = bh & 15;
    const bf16* src = arr ? vin : kin;
    bf16* dst = arr ? vT : kT;
    int tx = threadIdx.x, ty = threadIdx.y;
#pragma unroll
    for (int r = 0; r < 16; r++) {
        int lr = ty * 16 + r;
        tile[lr][tx] = src[(size_t)(b * S_ + x0 + lr) * 2048 + h * 128 + d0 + tx];
    }
    __syncthreads();
#pragma unroll
    for (int r = 0; r < 16; r++) {
        int lr = ty * 16 + r;
        dst[(size_t)(bh * 128 + d0 + lr) * S_ + x0 + tx] = tile[tx][lr];
    }
}

// ---------------------------------------------------------------------------
// Pass A: per (chunk c, b, h) compute KV^T[e][d] = sum_j vT[e][j]*kd[j]*kT[d][j]
// (kd[j]=exp(-s*(255-j))).  M=N=128, K=256.  Fragments straight from global.
// ---------------------------------------------------------------------------
__global__ __launch_bounds__(256) void pass_a_kernel(
        const bf16* __restrict__ kT, const bf16* __restrict__ vT,
        const float* __restrict__ slopes, bf16* __restrict__ KVT) {
    int c = blockIdx.x, bh = blockIdx.y;
    int tid = threadIdx.x, lane = tid & 63, wid = tid >> 6;
    int quad = lane >> 4, l15 = lane & 15;
    int e0 = (wid >> 1) * 64, d0 = (wid & 1) * 64;
    float s = slopes[bh & 15];
    float es = __expf(s);
    const bf16* vb = vT + (size_t)bh * 128 * S_ + c * 256;
    const bf16* kb = kT + (size_t)bh * 128 * S_ + c * 256;
    f32x4 acc[4][4] = {};
    for (int kbs = 0; kbs < 256; kbs += 32) {
        int j0 = kbs + quad * 8;
        float f[8];
        f[0] = __expf(-s * (float)(255 - j0));
#pragma unroll
        for (int jj = 1; jj < 8; jj++) f[jj] = f[jj - 1] * es;
        bf16x8 af[4], bfr[4];
#pragma unroll
        for (int t = 0; t < 4; t++)
            af[t] = *(const bf16x8*)(vb + (size_t)(e0 + t * 16 + l15) * S_ + j0);
#pragma unroll
        for (int t = 0; t < 4; t++) {
            bf16x8 raw = *(const bf16x8*)(kb + (size_t)(d0 + t * 16 + l15) * S_ + j0);
            bf16x8 sc;
#pragma unroll
            for (int jj = 0; jj < 8; jj++) sc[jj] = (bf16)((float)raw[jj] * f[jj]);
            bfr[t] = sc;
        }
#pragma unroll
        for (int ti = 0; ti < 4; ti++)
#pragma unroll
            for (int tj = 0; tj < 4; tj++)
                acc[ti][tj] = __builtin_amdgcn_mfma_f32_16x16x32_bf16(
                    af[ti], bfr[tj], acc[ti][tj], 0, 0, 0);
    }
    size_t base = ((size_t)c * 32 + bh) * 16384;
#pragma unroll
    for (int ti = 0; ti < 4; ti++)
#pragma unroll
        for (int tj = 0; tj < 4; tj++)
#pragma unroll
            for (int r = 0; r < 4; r++) {
                int e = e0 + ti * 16 + quad * 4 + r, d = d0 + tj * 16 + l15;
                KVT[base + (size_t)e * 128 + d] = (bf16)acc[ti][tj][r];
            }
}

// ---------------------------------------------------------------------------
// Pass B: decayed prefix scan of KV^T over chunks; stT[c] = state BEFORE c.
// ---------------------------------------------------------------------------
__global__ void scan_kernel(const bf16* __restrict__ KVT,
                            const float* __restrict__ slopes,
                            bf16* __restrict__ stT) {
    int slice = blockIdx.x, bh = blockIdx.y;
    float s = slopes[bh & 15];
    float bd = __expf(-s * 256.f);
    size_t off = (size_t)slice * 1024 + threadIdx.x * 4;
    float kv0 = 0.f, kv1 = 0.f, kv2 = 0.f, kv3 = 0.f;
    for (int c = 0; c < 16; c++) {
        size_t idx = ((size_t)c * 32 + bh) * 16384 + off;
        bf16x4 st;
        st[0] = (bf16)kv0; st[1] = (bf16)kv1; st[2] = (bf16)kv2; st[3] = (bf16)kv3;
        *(bf16x4*)(stT + idx) = st;
        bf16x4 kvc = *(const bf16x4*)(KVT + idx);
        kv0 = bd * kv0 + (float)kvc[0];
        kv1 = bd * kv1 + (float)kvc[1];
        kv2 = bd * kv2 + (float)kvc[2];
        kv3 = bd * kv3 + (float)kvc[3];
    }
}

// ---------------------------------------------------------------------------
// Pass C: o[i][e] = sum_j decay(i,j)(q_i.k_j) v[j][e] + qd[i]*(q_i @ state),
// then * sigmoid gate, bf16 store.  Wave w owns rows i0=w*64 x 128 e-cols.
// P round-trips through wave-private LDS rows (no barrier needed).
// ---------------------------------------------------------------------------
__global__ __launch_bounds__(256) void pass_c_kernel(
        const bf16* __restrict__ q, const bf16* __restrict__ kk,
        const bf16* __restrict__ vT, const bf16* __restrict__ stT,
        const bf16* __restrict__ gate, const float* __restrict__ slopes,
        bf16* __restrict__ og) {
    __shared__ __align__(16) bf16 P[256 * 72];
    __shared__ float dtab[257];
    int c = blockIdx.x, bh = blockIdx.y, b = bh >> 4, h = bh & 15;
    int tid = threadIdx.x, lane = tid & 63, wid = tid >> 6;
    int quad = lane >> 4, l15 = lane & 15;
    int i0 = wid * 64;
    float s = slopes[h];
    dtab[tid] = __expf(-s * (float)tid);
    if (tid == 0) dtab[256] = __expf(-s * 256.f);
    __syncthreads();
    const bf16* qb = q  + ((size_t)(b * S_ + c * 256)) * 2048 + h * 128;
    const bf16* kb = kk + ((size_t)(b * S_ + c * 256)) * 2048 + h * 128;
    const bf16* vb = vT + (size_t)bh * 128 * S_ + c * 256;
    const bf16* st = stT + ((size_t)c * 32 + bh) * 16384;
    f32x4 acc[4][8] = {};

    // inter-chunk: (q * q_decay) @ stateT rows, K=128
    for (int kbs = 0; kbs < 128; kbs += 32) {
        bf16x8 af[4];
#pragma unroll
        for (int t = 0; t < 4; t++) {
            int i = i0 + t * 16 + l15;
            float qd = dtab[i + 1];
            bf16x8 raw = *(const bf16x8*)(qb + (size_t)i * 2048 + kbs + quad * 8);
            bf16x8 sc;
#pragma unroll
            for (int jj = 0; jj < 8; jj++) sc[jj] = (bf16)((float)raw[jj] * qd);
            af[t] = sc;
        }
#pragma unroll
        for (int te = 0; te < 8; te++) {
            bf16x8 bfr = *(const bf16x8*)(st + (size_t)(te * 16 + l15) * 128 + kbs + quad * 8);
#pragma unroll
            for (int t = 0; t < 4; t++)
                acc[t][te] = __builtin_amdgcn_mfma_f32_16x16x32_bf16(
                    af[t], bfr, acc[t][te], 0, 0, 0);
        }
    }

    // intra-chunk, 4 j-tiles of 64
    for (int jt = 0; jt < 4; jt++) {
        f32x4 sacc[4][4] = {};
        for (int kbs = 0; kbs < 128; kbs += 32) {
            bf16x8 af[4], bkr[4];
#pragma unroll
            for (int t = 0; t < 4; t++)
                af[t] = *(const bf16x8*)(qb + (size_t)(i0 + t * 16 + l15) * 2048 + kbs + quad * 8);
#pragma unroll
            for (int t = 0; t < 4; t++)
                bkr[t] = *(const bf16x8*)(kb + (size_t)(jt * 64 + t * 16 + l15) * 2048 + kbs + quad * 8);
#pragma unroll
            for (int ti = 0; ti < 4; ti++)
#pragma unroll
                for (int tj = 0; tj < 4; tj++)
                    sacc[ti][tj] = __builtin_amdgcn_mfma_f32_16x16x32_bf16(
                        af[ti], bkr[tj], sacc[ti][tj], 0, 0, 0);
        }
        // causal decay, write P rows (wave-private)
#pragma unroll
        for (int ti = 0; ti < 4; ti++)
#pragma unroll
            for (int tj = 0; tj < 4; tj++)
#pragma unroll
                for (int r = 0; r < 4; r++) {
                    int i = i0 + ti * 16 + quad * 4 + r;
                    int j = jt * 64 + tj * 16 + l15;
                    int diff = i - j;
                    float pv = (diff >= 0) ? sacc[ti][tj][r] * dtab[diff] : 0.f;
                    P[i * 72 + tj * 16 + l15] = (bf16)pv;
                }
        // o += P @ vT rows, K=64
#pragma unroll
        for (int k2 = 0; k2 < 64; k2 += 32) {
            bf16x8 af[4];
#pragma unroll
            for (int t = 0; t < 4; t++)
                af[t] = *(const bf16x8*)&P[(i0 + t * 16 + l15) * 72 + k2 + quad * 8];
#pragma unroll
            for (int te = 0; te < 8; te++) {
                bf16x8 bfr = *(const bf16x8*)(vb + (size_t)(te * 16 + l15) * S_ + jt * 64 + k2 + quad * 8);
#pragma unroll
                for (int t = 0; t < 4; t++)
                    acc[t][te] = __builtin_amdgcn_mfma_f32_16x16x32_bf16(
                        af[t], bfr, acc[t][te], 0, 0, 0);
            }
        }
    }

    // epilogue: multiply gate, store bf16
    const bf16* gb = gate + ((size_t)(b * S_ + c * 256)) * 2048 + h * 128;
    bf16* ob = og + ((size_t)(b * S_ + c * 256)) * 2048 + h * 128;
#pragma unroll
    for (int ti = 0; ti < 4; ti++)
#pragma unroll
        for (int te = 0; te < 8; te++)
#pragma unroll
            for (int r = 0; r < 4; r++) {
                int i = i0 + ti * 16 + quad * 4 + r;
                int e = te * 16 + l15;
                float gv = (float)gb[(size_t)i * 2048 + e];
                ob[(size_t)i * 2048 + e] = (bf16)(acc[ti][te][r] * gv);
            }
}

// ---------------------------------------------------------------------------
// Workspace budget (d_ws): 200 MiB exactly.
//   wT 40 MiB + xb 32 + q 32 + k 32 + v 32 + g 32.
// kT aliases xb (dead after GEMM1).  vT/KVT/stT live in d_out (64 MiB f32),
// all dead before GEMM2 overwrites d_out.
// ---------------------------------------------------------------------------
extern "C" void kernel_launch(void* const* d_in, const int* in_sizes, int n_in,
                              void* d_out, int out_size, void* d_ws, size_t ws_size,
                              hipStream_t stream) {
    const float* x      = (const float*)d_in[0];
    const float* wqkv   = (const float*)d_in[1];
    const float* wgate  = (const float*)d_in[2];
    const float* wout   = (const float*)d_in[3];
    const float* slopes = (const float*)d_in[4];
    float* out = (float*)d_out;

    bf16* wT   = (bf16*)d_ws;                       // [10240][2048]  40 MiB
    bf16* xb   = wT   + (size_t)10240 * 2048;       // [8192][2048]   32 MiB
    bf16* qb   = xb   + (size_t)8192 * 2048;        // 32 MiB
    bf16* kbuf = qb   + (size_t)8192 * 2048;        // 32 MiB
    bf16* vbuf = kbuf + (size_t)8192 * 2048;        // 32 MiB (reused: gated attn)
    bf16* gbuf = vbuf + (size_t)8192 * 2048;        // 32 MiB
    bf16* kT   = xb;                                // alias: xb dead after GEMM1
    bf16* vT   = (bf16*)d_out;                      // [32][128][4096] 32 MiB
    bf16* KVT  = vT + (size_t)32 * 128 * 4096;      // [16][32][128][128] 16 MiB
    bf16* stT  = KVT + (size_t)16 * 32 * 16384;     // 16 MiB  (total = 64 MiB = d_out)

    cvt_x_kernel<<<dim3(8192), dim3(256), 0, stream>>>(x, xb);
    cvt_w_kernel<<<dim3(64, 320), dim3(32, 8), 0, stream>>>(wqkv, wgate, wout, wT);
    gemm_kernel<0><<<dim3(64, 64), dim3(256), 0, stream>>>(
        xb, wT, qb, kbuf, vbuf, gbuf, (float*)nullptr);
    transpose_kernel<<<dim3(64, 2, 64), dim3(64, 4), 0, stream>>>(kbuf, vbuf, kT, vT);
    pass_a_kernel<<<dim3(16, 32), dim3(256), 0, stream>>>(kT, vT, slopes, KVT);
    scan_kernel<<<dim3(16, 32), dim3(256), 0, stream>>>(KVT, slopes, stT);
    pass_c_kernel<<<dim3(16, 32), dim3(256), 0, stream>>>(
        qb, kbuf, vT, stT, gbuf, slopes, vbuf);
    gemm_kernel<1><<<dim3(64, 16), dim3(256), 0, stream>>>(
        vbuf, wT + (size_t)8192 * 2048, nullptr, nullptr, nullptr, nullptr, out);
}

// Round 3
// 741.480 us; speedup vs baseline: 1.0758x; 1.0758x over previous
//
#include <hip/hip_runtime.h>

typedef __bf16 bf16;
typedef __bf16 bf16x8 __attribute__((ext_vector_type(8)));
typedef __bf16 bf16x4 __attribute__((ext_vector_type(4)));
typedef float  f32x4  __attribute__((ext_vector_type(4)));

#define B_   2
#define S_   4096
#define HID_ 2048
#define H_   16
#define D_   128
#define C_   256
#define NC_  16
#define M_   (B_*S_)   // 8192 rows
#define K_   2048      // inner dim of both big GEMMs

typedef __attribute__((address_space(1))) const void gas_t;
typedef __attribute__((address_space(3))) void las_t;

// ---------------------------------------------------------------------------
// f32 -> bf16 convert of x (16.7M elements), 8 per thread
// ---------------------------------------------------------------------------
__global__ void cvt_x_kernel(const float* __restrict__ x, bf16* __restrict__ xb) {
    int idx = (blockIdx.x * 256 + threadIdx.x) * 8;
    float4 f0 = *(const float4*)(x + idx);
    float4 f1 = *(const float4*)(x + idx + 4);
    bf16x8 o;
    o[0] = (bf16)f0.x; o[1] = (bf16)f0.y; o[2] = (bf16)f0.z; o[3] = (bf16)f0.w;
    o[4] = (bf16)f1.x; o[5] = (bf16)f1.y; o[6] = (bf16)f1.z; o[7] = (bf16)f1.w;
    *(bf16x8*)(xb + idx) = o;
}

// ---------------------------------------------------------------------------
// Transpose-convert weights to bf16 [N][K]:
// rows 0..6143 = w_qkv cols, 6144..8191 = w_gate cols, 8192..10239 = w_out cols
// ---------------------------------------------------------------------------
__global__ void cvt_w_kernel(const float* __restrict__ wqkv,
                             const float* __restrict__ wgate,
                             const float* __restrict__ wout,
                             bf16* __restrict__ wT) {
    __shared__ float tile[32][33];
    int k0 = blockIdx.x * 32, n0 = blockIdx.y * 32;
    const float* src; int ld, col0;
    if (n0 < 6144)      { src = wqkv;  ld = 6144; col0 = n0; }
    else if (n0 < 8192) { src = wgate; ld = 2048; col0 = n0 - 6144; }
    else                { src = wout;  ld = 2048; col0 = n0 - 8192; }
    int tx = threadIdx.x, ty = threadIdx.y;
#pragma unroll
    for (int i = 0; i < 4; i++) {
        int kk = ty + i * 8;
        tile[kk][tx] = src[(size_t)(k0 + kk) * ld + col0 + tx];
    }
    __syncthreads();
#pragma unroll
    for (int i = 0; i < 4; i++) {
        int nn = ty + i * 8;
        wT[(size_t)(n0 + nn) * K_ + k0 + tx] = (bf16)tile[tx][nn];
    }
}

// ---------------------------------------------------------------------------
// bf16 GEMM, C[M][N] = act( A[M][K] @ B[N][K]^T ).  128x128 tile, 4 waves
// (2x2 of 64x64), BK=32, mfma 16x16x32 bf16, m97-style staging:
// global_load_lds width=16 into UNPADDED [128][32] LDS tiles (conflict-free
// for the b128 fragment reads: rows stride 16 banks, quads stride 4).
// MODE 0: N=8192, split output into q/k/v (silu) and gate (sigmoid), bf16.
// MODE 1: N=2048, plain f32 output to d_out.
// ---------------------------------------------------------------------------
template <int MODE>
__global__ __launch_bounds__(256) void gemm_kernel(
        const bf16* __restrict__ A, const bf16* __restrict__ Bm,
        bf16* __restrict__ qo, bf16* __restrict__ ko,
        bf16* __restrict__ vo, bf16* __restrict__ go,
        float* __restrict__ out) {
    __shared__ __align__(16) bf16 As[128 * 32];
    __shared__ __align__(16) bf16 Bs[128 * 32];
    const int m0 = blockIdx.x * 128, n0 = blockIdx.y * 128;
    const int tid = threadIdx.x, lane = tid & 63, wid = tid >> 6;
    const int quad = lane >> 4, l15 = lane & 15;
    const int i0w = (wid >> 1) * 64, j0w = (wid & 1) * 64;
    f32x4 acc[4][4] = {};
    // staging: thread tid covers LDS elements tid*8..tid*8+7 of the unpadded
    // [row][32] tile -> row = tid/4, k = (tid%4)*8.  Two calls cover 128 rows.
    const int srow = tid >> 2, scol = (tid & 3) * 8;
    const bf16* Ag = A  + (size_t)(m0 + srow) * K_ + scol;
    const bf16* Bg = Bm + (size_t)(n0 + srow) * K_ + scol;
    const size_t rowskip = (size_t)64 * K_;
    bf16* AsDst = As + tid * 8;
    bf16* BsDst = Bs + tid * 8;

    for (int kb = 0; kb < K_; kb += 32) {
        __builtin_amdgcn_global_load_lds((gas_t*)(Ag + kb),           (las_t*)AsDst,          16, 0, 0);
        __builtin_amdgcn_global_load_lds((gas_t*)(Ag + kb + rowskip), (las_t*)(AsDst + 2048), 16, 0, 0);
        __builtin_amdgcn_global_load_lds((gas_t*)(Bg + kb),           (las_t*)BsDst,          16, 0, 0);
        __builtin_amdgcn_global_load_lds((gas_t*)(Bg + kb + rowskip), (las_t*)(BsDst + 2048), 16, 0, 0);
        __syncthreads();
        bf16x8 af[4], bfr[4];
#pragma unroll
        for (int t = 0; t < 4; t++)
            af[t] = *(const bf16x8*)&As[(i0w + t * 16 + l15) * 32 + quad * 8];
#pragma unroll
        for (int t = 0; t < 4; t++)
            bfr[t] = *(const bf16x8*)&Bs[(j0w + t * 16 + l15) * 32 + quad * 8];
#pragma unroll
        for (int ti = 0; ti < 4; ti++)
#pragma unroll
            for (int tj = 0; tj < 4; tj++)
                acc[ti][tj] = __builtin_amdgcn_mfma_f32_16x16x32_bf16(
                    af[ti], bfr[tj], acc[ti][tj], 0, 0, 0);
        __syncthreads();
    }

    if (MODE == 0) {
        bf16* outb = (n0 < 2048) ? qo : (n0 < 4096) ? ko : (n0 < 6144) ? vo : go;
        const bool silu = (n0 < 6144);
        const int cb = n0 & 2047;
#pragma unroll
        for (int ti = 0; ti < 4; ti++)
#pragma unroll
            for (int tj = 0; tj < 4; tj++)
#pragma unroll
                for (int r = 0; r < 4; r++) {
                    int row = m0 + i0w + ti * 16 + quad * 4 + r;
                    int col = cb + j0w + tj * 16 + l15;
                    float xv = acc[ti][tj][r];
                    float sg = 1.f / (1.f + __expf(-xv));
                    float av = silu ? xv * sg : sg;
                    outb[(size_t)row * 2048 + col] = (bf16)av;
                }
    } else {
#pragma unroll
        for (int ti = 0; ti < 4; ti++)
#pragma unroll
            for (int tj = 0; tj < 4; tj++)
#pragma unroll
                for (int r = 0; r < 4; r++) {
                    int row = m0 + i0w + ti * 16 + quad * 4 + r;
                    int col = n0 + j0w + tj * 16 + l15;
                    out[(size_t)row * 2048 + col] = acc[ti][tj][r];
                }
    }
}

// ---------------------------------------------------------------------------
// Transpose k and v per (b,h): [S][D] -> [D][S]   (bf16, LDS 64x64 tiles)
// grid (S/64, D/64, 2*32): z = arr*32 + bh
// ---------------------------------------------------------------------------
__global__ void transpose_kernel(const bf16* __restrict__ kin,
                                 const bf16* __restrict__ vin,
                                 bf16* __restrict__ kT, bf16* __restrict__ vT) {
    __shared__ bf16 tile[64][65];
    int x0 = blockIdx.x * 64, d0 = blockIdx.y * 64;
    int z = blockIdx.z, arr = z >> 5, bh = z & 31, b = bh >> 4, h = bh & 15;
    const bf16* src = arr ? vin : kin;
    bf16* dst = arr ? vT : kT;
    int tx = threadIdx.x, ty = threadIdx.y;
#pragma unroll
    for (int r = 0; r < 16; r++) {
        int lr = ty * 16 + r;
        tile[lr][tx] = src[(size_t)(b * S_ + x0 + lr) * 2048 + h * 128 + d0 + tx];
    }
    __syncthreads();
#pragma unroll
    for (int r = 0; r < 16; r++) {
        int lr = ty * 16 + r;
        dst[(size_t)(bh * 128 + d0 + lr) * S_ + x0 + tx] = tile[tx][lr];
    }
}

// ---------------------------------------------------------------------------
// Pass A: per (chunk c, b, h) compute KV^T[e][d] = sum_j vT[e][j]*kd[j]*kT[d][j]
// (kd[j]=exp(-s*(255-j))).  M=N=128, K=256.  Fragments straight from global.
// ---------------------------------------------------------------------------
__global__ __launch_bounds__(256) void pass_a_kernel(
        const bf16* __restrict__ kT, const bf16* __restrict__ vT,
        const float* __restrict__ slopes, bf16* __restrict__ KVT) {
    int c = blockIdx.x, bh = blockIdx.y;
    int tid = threadIdx.x, lane = tid & 63, wid = tid >> 6;
    int quad = lane >> 4, l15 = lane & 15;
    int e0 = (wid >> 1) * 64, d0 = (wid & 1) * 64;
    float s = slopes[bh & 15];
    float es = __expf(s);
    const bf16* vb = vT + (size_t)bh * 128 * S_ + c * 256;
    const bf16* kb = kT + (size_t)bh * 128 * S_ + c * 256;
    f32x4 acc[4][4] = {};
    for (int kbs = 0; kbs < 256; kbs += 32) {
        int j0 = kbs + quad * 8;
        float f[8];
        f[0] = __expf(-s * (float)(255 - j0));
#pragma unroll
        for (int jj = 1; jj < 8; jj++) f[jj] = f[jj - 1] * es;
        bf16x8 af[4], bfr[4];
#pragma unroll
        for (int t = 0; t < 4; t++)
            af[t] = *(const bf16x8*)(vb + (size_t)(e0 + t * 16 + l15) * S_ + j0);
#pragma unroll
        for (int t = 0; t < 4; t++) {
            bf16x8 raw = *(const bf16x8*)(kb + (size_t)(d0 + t * 16 + l15) * S_ + j0);
            bf16x8 sc;
#pragma unroll
            for (int jj = 0; jj < 8; jj++) sc[jj] = (bf16)((float)raw[jj] * f[jj]);
            bfr[t] = sc;
        }
#pragma unroll
        for (int ti = 0; ti < 4; ti++)
#pragma unroll
            for (int tj = 0; tj < 4; tj++)
                acc[ti][tj] = __builtin_amdgcn_mfma_f32_16x16x32_bf16(
                    af[ti], bfr[tj], acc[ti][tj], 0, 0, 0);
    }
    size_t base = ((size_t)c * 32 + bh) * 16384;
#pragma unroll
    for (int ti = 0; ti < 4; ti++)
#pragma unroll
        for (int tj = 0; tj < 4; tj++)
#pragma unroll
            for (int r = 0; r < 4; r++) {
                int e = e0 + ti * 16 + quad * 4 + r, d = d0 + tj * 16 + l15;
                KVT[base + (size_t)e * 128 + d] = (bf16)acc[ti][tj][r];
            }
}

// ---------------------------------------------------------------------------
// Pass B: decayed prefix scan of KV^T over chunks; stT[c] = state BEFORE c.
// ---------------------------------------------------------------------------
__global__ void scan_kernel(const bf16* __restrict__ KVT,
                            const float* __restrict__ slopes,
                            bf16* __restrict__ stT) {
    int slice = blockIdx.x, bh = blockIdx.y;
    float s = slopes[bh & 15];
    float bd = __expf(-s * 256.f);
    size_t off = (size_t)slice * 1024 + threadIdx.x * 4;
    float kv0 = 0.f, kv1 = 0.f, kv2 = 0.f, kv3 = 0.f;
    for (int c = 0; c < 16; c++) {
        size_t idx = ((size_t)c * 32 + bh) * 16384 + off;
        bf16x4 st;
        st[0] = (bf16)kv0; st[1] = (bf16)kv1; st[2] = (bf16)kv2; st[3] = (bf16)kv3;
        *(bf16x4*)(stT + idx) = st;
        bf16x4 kvc = *(const bf16x4*)(KVT + idx);
        kv0 = bd * kv0 + (float)kvc[0];
        kv1 = bd * kv1 + (float)kvc[1];
        kv2 = bd * kv2 + (float)kvc[2];
        kv3 = bd * kv3 + (float)kvc[3];
    }
}

// ---------------------------------------------------------------------------
// Pass C: o[i][e] = sum_j decay(i,j)(q_i.k_j) v[j][e] + qd[i]*(q_i @ state),
// then * sigmoid gate, bf16 store.  Wave w owns rows i0=w*64 x 128 e-cols.
// P round-trips through wave-private LDS rows (no barrier needed).
// ---------------------------------------------------------------------------
__global__ __launch_bounds__(256) void pass_c_kernel(
        const bf16* __restrict__ q, const bf16* __restrict__ kk,
        const bf16* __restrict__ vT, const bf16* __restrict__ stT,
        const bf16* __restrict__ gate, const float* __restrict__ slopes,
        bf16* __restrict__ og) {
    __shared__ __align__(16) bf16 P[256 * 72];
    __shared__ float dtab[257];
    int c = blockIdx.x, bh = blockIdx.y, b = bh >> 4, h = bh & 15;
    int tid = threadIdx.x, lane = tid & 63, wid = tid >> 6;
    int quad = lane >> 4, l15 = lane & 15;
    int i0 = wid * 64;
    float s = slopes[h];
    dtab[tid] = __expf(-s * (float)tid);
    if (tid == 0) dtab[256] = __expf(-s * 256.f);
    __syncthreads();
    const bf16* qb = q  + ((size_t)(b * S_ + c * 256)) * 2048 + h * 128;
    const bf16* kb = kk + ((size_t)(b * S_ + c * 256)) * 2048 + h * 128;
    const bf16* vb = vT + (size_t)bh * 128 * S_ + c * 256;
    const bf16* st = stT + ((size_t)c * 32 + bh) * 16384;
    f32x4 acc[4][8] = {};

    // inter-chunk: (q * q_decay) @ stateT rows, K=128
    for (int kbs = 0; kbs < 128; kbs += 32) {
        bf16x8 af[4];
#pragma unroll
        for (int t = 0; t < 4; t++) {
            int i = i0 + t * 16 + l15;
            float qd = dtab[i + 1];
            bf16x8 raw = *(const bf16x8*)(qb + (size_t)i * 2048 + kbs + quad * 8);
            bf16x8 sc;
#pragma unroll
            for (int jj = 0; jj < 8; jj++) sc[jj] = (bf16)((float)raw[jj] * qd);
            af[t] = sc;
        }
#pragma unroll
        for (int te = 0; te < 8; te++) {
            bf16x8 bfr = *(const bf16x8*)(st + (size_t)(te * 16 + l15) * 128 + kbs + quad * 8);
#pragma unroll
            for (int t = 0; t < 4; t++)
                acc[t][te] = __builtin_amdgcn_mfma_f32_16x16x32_bf16(
                    af[t], bfr, acc[t][te], 0, 0, 0);
        }
    }

    // intra-chunk, 4 j-tiles of 64
    for (int jt = 0; jt < 4; jt++) {
        f32x4 sacc[4][4] = {};
        for (int kbs = 0; kbs < 128; kbs += 32) {
            bf16x8 af[4], bkr[4];
#pragma unroll
            for (int t = 0; t < 4; t++)
                af[t] = *(const bf16x8*)(qb + (size_t)(i0 + t * 16 + l15) * 2048 + kbs + quad * 8);
#pragma unroll
            for (int t = 0; t < 4; t++)
                bkr[t] = *(const bf16x8*)(kb + (size_t)(jt * 64 + t * 16 + l15) * 2048 + kbs + quad * 8);
#pragma unroll
            for (int ti = 0; ti < 4; ti++)
#pragma unroll
                for (int tj = 0; tj < 4; tj++)
                    sacc[ti][tj] = __builtin_amdgcn_mfma_f32_16x16x32_bf16(
                        af[ti], bkr[tj], sacc[ti][tj], 0, 0, 0);
        }
        // causal decay, write P rows (wave-private)
#pragma unroll
        for (int ti = 0; ti < 4; ti++)
#pragma unroll
            for (int tj = 0; tj < 4; tj++)
#pragma unroll
                for (int r = 0; r < 4; r++) {
                    int i = i0 + ti * 16 + quad * 4 + r;
                    int j = jt * 64 + tj * 16 + l15;
                    int diff = i - j;
                    float pv = (diff >= 0) ? sacc[ti][tj][r] * dtab[diff] : 0.f;
                    P[i * 72 + tj * 16 + l15] = (bf16)pv;
                }
        // o += P @ vT rows, K=64
#pragma unroll
        for (int k2 = 0; k2 < 64; k2 += 32) {
            bf16x8 af[4];
#pragma unroll
            for (int t = 0; t < 4; t++)
                af[t] = *(const bf16x8*)&P[(i0 + t * 16 + l15) * 72 + k2 + quad * 8];
#pragma unroll
            for (int te = 0; te < 8; te++) {
                bf16x8 bfr = *(const bf16x8*)(vb + (size_t)(te * 16 + l15) * S_ + jt * 64 + k2 + quad * 8);
#pragma unroll
                for (int t = 0; t < 4; t++)
                    acc[t][te] = __builtin_amdgcn_mfma_f32_16x16x32_bf16(
                        af[t], bfr, acc[t][te], 0, 0, 0);
            }
        }
    }

    // epilogue: multiply gate, store bf16
    const bf16* gb = gate + ((size_t)(b * S_ + c * 256)) * 2048 + h * 128;
    bf16* ob = og + ((size_t)(b * S_ + c * 256)) * 2048 + h * 128;
#pragma unroll
    for (int ti = 0; ti < 4; ti++)
#pragma unroll
        for (int te = 0; te < 8; te++)
#pragma unroll
            for (int r = 0; r < 4; r++) {
                int i = i0 + ti * 16 + quad * 4 + r;
                int e = te * 16 + l15;
                float gv = (float)gb[(size_t)i * 2048 + e];
                ob[(size_t)i * 2048 + e] = (bf16)(acc[ti][te][r] * gv);
            }
}

// ---------------------------------------------------------------------------
// Workspace budget (d_ws): 200 MiB exactly.
//   wT 40 MiB + xb 32 + q 32 + k 32 + v 32 + g 32.
// kT aliases xb (dead after GEMM1).  vT/KVT/stT live in d_out (64 MiB f32),
// all dead before GEMM2 overwrites d_out.
// ---------------------------------------------------------------------------
extern "C" void kernel_launch(void* const* d_in, const int* in_sizes, int n_in,
                              void* d_out, int out_size, void* d_ws, size_t ws_size,
                              hipStream_t stream) {
    const float* x      = (const float*)d_in[0];
    const float* wqkv   = (const float*)d_in[1];
    const float* wgate  = (const float*)d_in[2];
    const float* wout   = (const float*)d_in[3];
    const float* slopes = (const float*)d_in[4];
    float* out = (float*)d_out;

    bf16* wT   = (bf16*)d_ws;                       // [10240][2048]  40 MiB
    bf16* xb   = wT   + (size_t)10240 * 2048;       // [8192][2048]   32 MiB
    bf16* qb   = xb   + (size_t)8192 * 2048;        // 32 MiB
    bf16* kbuf = qb   + (size_t)8192 * 2048;        // 32 MiB
    bf16* vbuf = kbuf + (size_t)8192 * 2048;        // 32 MiB (reused: gated attn)
    bf16* gbuf = vbuf + (size_t)8192 * 2048;        // 32 MiB
    bf16* kT   = xb;                                // alias: xb dead after GEMM1
    bf16* vT   = (bf16*)d_out;                      // [32][128][4096] 32 MiB
    bf16* KVT  = vT + (size_t)32 * 128 * 4096;      // [16][32][128][128] 16 MiB
    bf16* stT  = KVT + (size_t)16 * 32 * 16384;     // 16 MiB  (total = 64 MiB = d_out)

    cvt_x_kernel<<<dim3(8192), dim3(256), 0, stream>>>(x, xb);
    cvt_w_kernel<<<dim3(64, 320), dim3(32, 8), 0, stream>>>(wqkv, wgate, wout, wT);
    gemm_kernel<0><<<dim3(64, 64), dim3(256), 0, stream>>>(
        xb, wT, qb, kbuf, vbuf, gbuf, (float*)nullptr);
    transpose_kernel<<<dim3(64, 2, 64), dim3(64, 4), 0, stream>>>(kbuf, vbuf, kT, vT);
    pass_a_kernel<<<dim3(16, 32), dim3(256), 0, stream>>>(kT, vT, slopes, KVT);
    scan_kernel<<<dim3(16, 32), dim3(256), 0, stream>>>(KVT, slopes, stT);
    pass_c_kernel<<<dim3(16, 32), dim3(256), 0, stream>>>(
        qb, kbuf, vT, stT, gbuf, slopes, vbuf);
    gemm_kernel<1><<<dim3(64, 16), dim3(256), 0, stream>>>(
        vbuf, wT + (size_t)8192 * 2048, nullptr, nullptr, nullptr, nullptr, out);
}